// Round 1
// baseline (130.486 us; speedup 1.0000x reference)
//
#include <hip/hip_runtime.h>

// Problem constants: B=2, N_mm=64, N_a=N_v=256, DIM=512, H=8, hd=64, scale=1/8.
// Workspace layout (floats):
#define WS_Q    0          // q = xmm@Wq.T            [128][512]
#define WS_PV   65536      // pv = xv@Wkv[:,:512].T   [512][1024]
#define WS_PA   589824     // pa = xa@Wkv[:,512:].T   [512][1024]
#define WS_HOUT 1114112    // pre-proj attention out  [128][512]
// total 1179648 floats = 4.5 MB

// ---------------------------------------------------------------------------
// GEMM C[M,N] = A[M,K=512] @ W[N,K=512]^T (+bias), 64x64 tile, 128 threads,
// thread tile 4 rows x 8 cols (ratio 10.7 FMA per ds_read_b128).
// LDS rows padded to 40 dwords + XOR chunk swizzle to spread banks.
// ---------------------------------------------------------------------------
__device__ __forceinline__ void gemm64_body(
    const float* __restrict__ A, int lda,
    const float* __restrict__ W, int ldw,
    float* __restrict__ C, int ldc,
    int bm, int bn, const float* __restrict__ bias)
{
  __shared__ float As[64][40];
  __shared__ float Ws[64][40];
  const int tid = threadIdx.x;          // 128 threads
  const int tx = tid & 7;               // col group: cols = tx + 8j
  const int ty = tid >> 3;              // row group: rows = 4ty + i  (0..15)
  float acc[4][8];
  #pragma unroll
  for (int i = 0; i < 4; ++i)
    #pragma unroll
    for (int j = 0; j < 8; ++j) acc[i][j] = 0.f;

  for (int k0 = 0; k0 < 512; k0 += 32) {
    #pragma unroll
    for (int s = 0; s < 4; ++s) {
      int idx = tid + s * 128;          // 0..511
      int r = idx >> 3, c4 = idx & 7;
      float4 av = *reinterpret_cast<const float4*>(&A[(size_t)(bm + r) * lda + k0 + c4 * 4]);
      float4 wv = *reinterpret_cast<const float4*>(&W[(size_t)(bn + r) * ldw + k0 + c4 * 4]);
      int pc = c4 ^ (r & 7);
      *reinterpret_cast<float4*>(&As[r][pc * 4]) = av;
      *reinterpret_cast<float4*>(&Ws[r][pc * 4]) = wv;
    }
    __syncthreads();
    #pragma unroll
    for (int kc = 0; kc < 8; ++kc) {
      float4 a4[4], w4[8];
      #pragma unroll
      for (int i = 0; i < 4; ++i) {
        int r = ty * 4 + i;
        a4[i] = *reinterpret_cast<const float4*>(&As[r][((kc ^ (r & 7)) * 4)]);
      }
      const int wchunk = (kc ^ tx) * 4; // (tx+8j)&7 == tx
      #pragma unroll
      for (int j = 0; j < 8; ++j)
        w4[j] = *reinterpret_cast<const float4*>(&Ws[tx + 8 * j][wchunk]);
      #pragma unroll
      for (int i = 0; i < 4; ++i)
        #pragma unroll
        for (int j = 0; j < 8; ++j)
          acc[i][j] += a4[i].x * w4[j].x + a4[i].y * w4[j].y
                     + a4[i].z * w4[j].z + a4[i].w * w4[j].w;
    }
    __syncthreads();
  }
  #pragma unroll
  for (int i = 0; i < 4; ++i) {
    int r = bm + ty * 4 + i;
    #pragma unroll
    for (int j = 0; j < 8; ++j) {
      int c = bn + tx + 8 * j;
      float v = acc[i][j];
      if (bias) v += bias[c];
      C[(size_t)r * ldc + c] = v;
    }
  }
}

// 32x32 tile, 64 threads, 4x4 thread tile (for the small output projection:
// more blocks -> more CUs busy; 1 wave/block keeps LDS pipe under VALU).
__device__ __forceinline__ void gemm32_body(
    const float* __restrict__ A, int lda,
    const float* __restrict__ W, int ldw,
    float* __restrict__ C, int ldc,
    int bm, int bn, const float* __restrict__ bias)
{
  __shared__ float As[32][40];
  __shared__ float Ws[32][40];
  const int tid = threadIdx.x;          // 64 threads
  const int tx = tid & 7;               // cols = tx + 8j, j<4
  const int ty = tid >> 3;              // rows = 4ty + i (0..7)
  float acc[4][4];
  #pragma unroll
  for (int i = 0; i < 4; ++i)
    #pragma unroll
    for (int j = 0; j < 4; ++j) acc[i][j] = 0.f;

  for (int k0 = 0; k0 < 512; k0 += 32) {
    #pragma unroll
    for (int s = 0; s < 4; ++s) {
      int idx = tid + s * 64;           // 0..255
      int r = idx >> 3, c4 = idx & 7;
      float4 av = *reinterpret_cast<const float4*>(&A[(size_t)(bm + r) * lda + k0 + c4 * 4]);
      float4 wv = *reinterpret_cast<const float4*>(&W[(size_t)(bn + r) * ldw + k0 + c4 * 4]);
      int pc = c4 ^ (r & 7);
      *reinterpret_cast<float4*>(&As[r][pc * 4]) = av;
      *reinterpret_cast<float4*>(&Ws[r][pc * 4]) = wv;
    }
    __syncthreads();
    #pragma unroll
    for (int kc = 0; kc < 8; ++kc) {
      float4 a4[4], w4[4];
      #pragma unroll
      for (int i = 0; i < 4; ++i) {
        int r = ty * 4 + i;
        a4[i] = *reinterpret_cast<const float4*>(&As[r][((kc ^ (r & 7)) * 4)]);
      }
      const int wchunk = (kc ^ tx) * 4;
      #pragma unroll
      for (int j = 0; j < 4; ++j)
        w4[j] = *reinterpret_cast<const float4*>(&Ws[tx + 8 * j][wchunk]);
      #pragma unroll
      for (int i = 0; i < 4; ++i)
        #pragma unroll
        for (int j = 0; j < 4; ++j)
          acc[i][j] += a4[i].x * w4[j].x + a4[i].y * w4[j].y
                     + a4[i].z * w4[j].z + a4[i].w * w4[j].w;
    }
    __syncthreads();
  }
  #pragma unroll
  for (int i = 0; i < 4; ++i) {
    int r = bm + ty * 4 + i;
    #pragma unroll
    for (int j = 0; j < 4; ++j) {
      int c = bn + tx + 8 * j;
      float v = acc[i][j];
      if (bias) v += bias[c];
      C[(size_t)r * ldc + c] = v;
    }
  }
}

// K1: fused q / pv / pa projections. 272 blocks x 128 threads.
__global__ __launch_bounds__(128) void fused_proj_kernel(
    const float* __restrict__ xmm, const float* __restrict__ xa,
    const float* __restrict__ xv, const float* __restrict__ Wq,
    const float* __restrict__ Wkv, float* __restrict__ ws)
{
  const int id = blockIdx.x;
  if (id < 16) {                        // q: M=128, N=512 -> 2x8 tiles
    gemm64_body(xmm, 512, Wq, 512, ws + WS_Q, 512,
                (id >> 3) * 64, (id & 7) * 64, nullptr);
  } else if (id < 144) {                // pv: M=512, N=1024 -> 8x16 tiles
    int t = id - 16;
    gemm64_body(xv, 512, Wkv, 1024, ws + WS_PV, 1024,
                (t >> 4) * 64, (t & 15) * 64, nullptr);
  } else {                              // pa: uses Wkv[:, 512:]
    int t = id - 144;
    gemm64_body(xa, 512, Wkv + 512, 1024, ws + WS_PA, 1024,
                (t >> 4) * 64, (t & 15) * 64, nullptr);
  }
}

// K3: out = hout @ Wproj.T + bproj. M=128,N=512 -> 4x16 = 64 blocks x 64 thr.
__global__ __launch_bounds__(64) void proj_out_kernel(
    const float* __restrict__ ws, const float* __restrict__ Wproj,
    const float* __restrict__ bproj, float* __restrict__ out)
{
  gemm32_body(ws + WS_HOUT, 512, Wproj, 512, out, 512,
              (int)(blockIdx.x >> 4) * 32, (int)(blockIdx.x & 15) * 32, bproj);
}

// ---------------------------------------------------------------------------
// K2: factorized attention. Grid = 16 (b,h) x 4 q-row-tiles = 64 blocks,
// 256 threads (4 waves). For each side s in {pv, pa}:
//   A[n,i] = (scale*q[n,:]) . kpart[i,:]   (kpart = side[:, h*64 : h*64+64])
//   P = softmax_i(A) (wave-parallel over 256 keys, rows held in registers)
//   oacc += P @ vpart                      (vpart = side[:, 512+h*64 : ...])
// K/V staged to LDS in 128-row halves to stay under 64KB static LDS.
// ---------------------------------------------------------------------------
__global__ __launch_bounds__(256) void attn_kernel(float* __restrict__ ws)
{
  const float* qlin = ws + WS_Q;
  float* hout = ws + WS_HOUT;

  const int blk = blockIdx.x;
  const int bh = blk >> 2;              // 0..15
  const int ntile = blk & 3;            // 0..3 (16 q-rows each)
  const int b = bh >> 3, h = bh & 7;
  const int n0 = ntile * 16;

  __shared__ float q_s[16][64];         // 4 KB  (scaled q tile)
  __shared__ float kv_s[128][68];       // 34 KB (K or V half, padded)
  __shared__ float P_s[16][260];        // 16.25 KB (normalized probs)
  // reduction buffer aliases kv_s after last PV (needs 4*16*64 = 4096 floats)

  const int tid = threadIdx.x;
  const int w = tid >> 6;               // wave 0..3
  const int lane = tid & 63;

  { // stage q, folding in scale = 1/8
    int r = tid >> 4, c = tid & 15;
    float4 v = *reinterpret_cast<const float4*>(
        &qlin[(size_t)(b * 64 + n0 + r) * 512 + h * 64 + c * 4]);
    v.x *= 0.125f; v.y *= 0.125f; v.z *= 0.125f; v.w *= 0.125f;
    *reinterpret_cast<float4*>(&q_s[r][c * 4]) = v;
  }

  float4 oacc[2][2];
  #pragma unroll
  for (int r = 0; r < 2; ++r)
    #pragma unroll
    for (int c = 0; c < 2; ++c) oacc[r][c] = make_float4(0.f, 0.f, 0.f, 0.f);

  const int gn2 = lane >> 3;            // PV: rows 2*gn2 + {0,1}
  const int gd2 = lane & 7;             // PV: d-chunks 2*gd2 + {0,1}

  for (int side = 0; side < 2; ++side) {
    const float* src = (side == 0) ? (ws + WS_PV) : (ws + WS_PA);

    // ---- scores: sc[ni][ii] = logit for row (4w+ni), key (lane + 64*ii)
    float sc[4][4];
    #pragma unroll
    for (int i = 0; i < 4; ++i)
      #pragma unroll
      for (int j = 0; j < 4; ++j) sc[i][j] = 0.f;

    for (int half = 0; half < 2; ++half) {
      __syncthreads();                  // prev phase done reading kv_s
      #pragma unroll
      for (int s = 0; s < 8; ++s) {     // stage K half: 128 rows x 16 chunks
        int idx = tid + s * 256;
        int r = idx >> 4, c = idx & 15;
        *reinterpret_cast<float4*>(&kv_s[r][c * 4]) =
          *reinterpret_cast<const float4*>(
            &src[(size_t)(b * 256 + half * 128 + r) * 1024 + h * 64 + c * 4]);
      }
      __syncthreads();
      #pragma unroll
      for (int dc = 0; dc < 16; ++dc) {
        float4 q4[4], k4[2];
        #pragma unroll
        for (int ni = 0; ni < 4; ++ni)
          q4[ni] = *reinterpret_cast<const float4*>(&q_s[w * 4 + ni][dc * 4]);
        #pragma unroll
        for (int i2 = 0; i2 < 2; ++i2)
          k4[i2] = *reinterpret_cast<const float4*>(&kv_s[lane + 64 * i2][dc * 4]);
        #pragma unroll
        for (int ni = 0; ni < 4; ++ni)
          #pragma unroll
          for (int i2 = 0; i2 < 2; ++i2)
            sc[ni][half * 2 + i2] += q4[ni].x * k4[i2].x + q4[ni].y * k4[i2].y
                                   + q4[ni].z * k4[i2].z + q4[ni].w * k4[i2].w;
      }
    }

    // ---- softmax (per q-row, wave-wide over 256 keys; key i = lane + 64*ii)
    #pragma unroll
    for (int ni = 0; ni < 4; ++ni) {
      float m = fmaxf(fmaxf(sc[ni][0], sc[ni][1]), fmaxf(sc[ni][2], sc[ni][3]));
      #pragma unroll
      for (int off = 32; off >= 1; off >>= 1)
        m = fmaxf(m, __shfl_xor(m, off));
      float e[4], ls = 0.f;
      #pragma unroll
      for (int ii = 0; ii < 4; ++ii) { e[ii] = __expf(sc[ni][ii] - m); ls += e[ii]; }
      #pragma unroll
      for (int off = 32; off >= 1; off >>= 1)
        ls += __shfl_xor(ls, off);
      float inv = 1.0f / ls;
      #pragma unroll
      for (int ii = 0; ii < 4; ++ii)
        P_s[w * 4 + ni][lane + 64 * ii] = e[ii] * inv;
    }

    // ---- PV: out[n][d] += sum_i P[n][i] * v[i][d], V staged in halves;
    // waves split i (32 per wave per half), partials reduced at the end.
    for (int half = 0; half < 2; ++half) {
      __syncthreads();                  // scores/PV done reading kv_s; P_s written
      #pragma unroll
      for (int s = 0; s < 8; ++s) {     // stage V half (cols 512 + h*64 ..)
        int idx = tid + s * 256;
        int r = idx >> 4, c = idx & 15;
        *reinterpret_cast<float4*>(&kv_s[r][c * 4]) =
          *reinterpret_cast<const float4*>(
            &src[(size_t)(b * 256 + half * 128 + r) * 1024 + 512 + h * 64 + c * 4]);
      }
      __syncthreads();
      #pragma unroll
      for (int ic = 0; ic < 8; ++ic) {
        int i0l = w * 32 + ic * 4;          // local row in kv_s
        int i0g = half * 128 + i0l;         // column in P_s
        float4 p4[2];
        #pragma unroll
        for (int r = 0; r < 2; ++r)
          p4[r] = *reinterpret_cast<const float4*>(&P_s[gn2 * 2 + r][i0g]);
        float4 v4[4][2];
        #pragma unroll
        for (int m = 0; m < 4; ++m)
          #pragma unroll
          for (int c = 0; c < 2; ++c)
            v4[m][c] = *reinterpret_cast<const float4*>(&kv_s[i0l + m][(gd2 * 2 + c) * 4]);
        #pragma unroll
        for (int r = 0; r < 2; ++r)
          #pragma unroll
          for (int c = 0; c < 2; ++c) {
            oacc[r][c].x += p4[r].x * v4[0][c].x + p4[r].y * v4[1][c].x
                          + p4[r].z * v4[2][c].x + p4[r].w * v4[3][c].x;
            oacc[r][c].y += p4[r].x * v4[0][c].y + p4[r].y * v4[1][c].y
                          + p4[r].z * v4[2][c].y + p4[r].w * v4[3][c].y;
            oacc[r][c].z += p4[r].x * v4[0][c].z + p4[r].y * v4[1][c].z
                          + p4[r].z * v4[2][c].z + p4[r].w * v4[3][c].z;
            oacc[r][c].w += p4[r].x * v4[0][c].w + p4[r].y * v4[1][c].w
                          + p4[r].z * v4[2][c].w + p4[r].w * v4[3][c].w;
          }
      }
    }
  } // side

  // ---- cross-wave reduction of PV partials (reuse kv_s as [4][16][64])
  __syncthreads();                      // everyone done reading kv_s as V
  float* red = &kv_s[0][0];
  #pragma unroll
  for (int r = 0; r < 2; ++r)
    #pragma unroll
    for (int c = 0; c < 2; ++c)
      *reinterpret_cast<float4*>(
        &red[(size_t)w * 1024 + (gn2 * 2 + r) * 64 + (gd2 * 2 + c) * 4]) = oacc[r][c];
  __syncthreads();
  {
    int n = tid >> 4, dc = tid & 15;
    float4 sum = *reinterpret_cast<const float4*>(&red[(size_t)n * 64 + dc * 4]);
    #pragma unroll
    for (int ww = 1; ww < 4; ++ww) {
      float4 t = *reinterpret_cast<const float4*>(
          &red[(size_t)ww * 1024 + n * 64 + dc * 4]);
      sum.x += t.x; sum.y += t.y; sum.z += t.z; sum.w += t.w;
    }
    *reinterpret_cast<float4*>(
        &hout[(size_t)(b * 64 + n0 + n) * 512 + h * 64 + dc * 4]) = sum;
  }
}

extern "C" void kernel_launch(void* const* d_in, const int* in_sizes, int n_in,
                              void* d_out, int out_size, void* d_ws, size_t ws_size,
                              hipStream_t stream) {
  const float* xmm   = (const float*)d_in[0];  // [2,64,512]
  const float* xa    = (const float*)d_in[1];  // [2,256,512]
  const float* xv    = (const float*)d_in[2];  // [2,256,512]
  const float* Wq    = (const float*)d_in[3];  // [512,512]
  const float* Wkv   = (const float*)d_in[4];  // [1024,1024]
  const float* Wproj = (const float*)d_in[5];  // [512,512]
  const float* bproj = (const float*)d_in[6];  // [512]
  float* out = (float*)d_out;                  // [2,64,512]
  float* ws  = (float*)d_ws;                   // needs 4.5 MB

  fused_proj_kernel<<<272, 128, 0, stream>>>(xmm, xa, xv, Wq, Wkv, ws);
  attn_kernel<<<64, 256, 0, stream>>>(ws);
  proj_out_kernel<<<64, 64, 0, stream>>>(ws, Wproj, bproj, out);
}

// Round 2
// 50.588 us; speedup vs baseline: 2.5794x; 2.5794x over previous
//
#include <hip/hip_runtime.h>

// Problem constants: B=2, N_mm=64, N_a=N_v=256, DIM=512, H=8, hd=64, scale=1/8.
// Factorization: softmax over the (i,j) product grid with logits A_i+B_j and
// values pvv_i+pav_j separates EXACTLY into two 256-key attentions.
//
// Workspace layout (floats):
#define WS_Q    0          // q = xmm@Wq.T            [128][512]
#define WS_PV   65536      // pv = xv@Wkv[:,:512].T   [512][1024]
#define WS_PA   589824     // pa = xa@Wkv[:,512:].T   [512][1024]
#define WS_HOUT 1114112    // pre-proj attention out  [128][512]
// total 1179648 floats = 4.5 MB

typedef _Float16 f16x8 __attribute__((ext_vector_type(8)));
typedef float f32x4 __attribute__((ext_vector_type(4)));

// ---------------------------------------------------------------------------
// MFMA f16 GEMM: C[M,N] = A[M,K=512] @ W[N,K=512]^T (+bias).
// 64x64 tile, 256 threads (4 waves, 2x2), each wave 32x32 out.
// Inputs fp32; staging converts to f16 in registers, writes swizzled LDS
// (XOR 16B-chunk swizzle: chunk ^= row&7  -> 2-way conflicts only, free).
// MFMA 16x16x32_f16, fp32 accum. A-frag: row=lane&15, k=(lane>>4)*8+j;
// B-frag: col=lane&15 same k; C/D: col=lane&15, row=(lane>>4)*4+reg.
// ---------------------------------------------------------------------------
__device__ __forceinline__ void stage_tile_f16(
    const float* __restrict__ g, int ld, int base, int k0,
    _Float16* __restrict__ lds, int sr, int sq)
{
  const float* p = &g[(size_t)(base + sr) * ld + k0 + sq * 16];
  float4 v0 = *reinterpret_cast<const float4*>(p);
  float4 v1 = *reinterpret_cast<const float4*>(p + 4);
  float4 v2 = *reinterpret_cast<const float4*>(p + 8);
  float4 v3 = *reinterpret_cast<const float4*>(p + 12);
  f16x8 h0 = {(_Float16)v0.x, (_Float16)v0.y, (_Float16)v0.z, (_Float16)v0.w,
              (_Float16)v1.x, (_Float16)v1.y, (_Float16)v1.z, (_Float16)v1.w};
  f16x8 h1 = {(_Float16)v2.x, (_Float16)v2.y, (_Float16)v2.z, (_Float16)v2.w,
              (_Float16)v3.x, (_Float16)v3.y, (_Float16)v3.z, (_Float16)v3.w};
  int c0 = (sq * 2) ^ (sr & 7);
  int c1 = (sq * 2 + 1) ^ (sr & 7);
  *reinterpret_cast<f16x8*>(&lds[sr * 64 + c0 * 8]) = h0;
  *reinterpret_cast<f16x8*>(&lds[sr * 64 + c1 * 8]) = h1;
}

__device__ __forceinline__ void mfma_gemm64(
    const float* __restrict__ A, int lda,
    const float* __restrict__ W, int ldw,
    float* __restrict__ C, int ldc,
    int bm, int bn, const float* __restrict__ bias)
{
  __shared__ _Float16 As[64 * 64];   // 8 KB
  __shared__ _Float16 Ws[64 * 64];   // 8 KB
  const int tid = threadIdx.x;
  const int lane = tid & 63;
  const int w = tid >> 6;
  const int wm = w >> 1, wn = w & 1;
  const int sr = tid >> 2;           // staging row 0..63
  const int sq = tid & 3;            // staging 16-float segment 0..3

  f32x4 acc[2][2] = {};

  const int cl = lane & 15;          // fragment row/col within 16
  const int kg = lane >> 4;          // k-group 0..3

  for (int k0 = 0; k0 < 512; k0 += 64) {
    __syncthreads();
    stage_tile_f16(A, lda, bm, k0, As, sr, sq);
    stage_tile_f16(W, ldw, bn, k0, Ws, sr, sq);
    __syncthreads();
    #pragma unroll
    for (int ks = 0; ks < 2; ++ks) {
      f16x8 af[2], bf[2];
      #pragma unroll
      for (int mi = 0; mi < 2; ++mi) {
        int row = wm * 32 + mi * 16 + cl;
        int ch = (ks * 4 + kg) ^ (row & 7);
        af[mi] = *reinterpret_cast<const f16x8*>(&As[row * 64 + ch * 8]);
      }
      #pragma unroll
      for (int ni = 0; ni < 2; ++ni) {
        int col = wn * 32 + ni * 16 + cl;
        int ch = (ks * 4 + kg) ^ (col & 7);
        bf[ni] = *reinterpret_cast<const f16x8*>(&Ws[col * 64 + ch * 8]);
      }
      #pragma unroll
      for (int mi = 0; mi < 2; ++mi)
        #pragma unroll
        for (int ni = 0; ni < 2; ++ni)
          acc[mi][ni] = __builtin_amdgcn_mfma_f32_16x16x32_f16(
              af[mi], bf[ni], acc[mi][ni], 0, 0, 0);
    }
  }

  #pragma unroll
  for (int mi = 0; mi < 2; ++mi) {
    #pragma unroll
    for (int ni = 0; ni < 2; ++ni) {
      int row0 = bm + wm * 32 + mi * 16 + kg * 4;
      int col = bn + wn * 32 + ni * 16 + cl;
      float bv = bias ? bias[col] : 0.f;
      #pragma unroll
      for (int r = 0; r < 4; ++r)
        C[(size_t)(row0 + r) * ldc + col] = acc[mi][ni][r] + bv;
    }
  }
}

// K1: fused q / pv / pa projections. 272 blocks x 256 threads.
__global__ __launch_bounds__(256) void fused_proj_kernel(
    const float* __restrict__ xmm, const float* __restrict__ xa,
    const float* __restrict__ xv, const float* __restrict__ Wq,
    const float* __restrict__ Wkv, float* __restrict__ ws)
{
  const int id = blockIdx.x;
  if (id < 16) {                        // q: M=128, N=512 -> 2x8 tiles
    mfma_gemm64(xmm, 512, Wq, 512, ws + WS_Q, 512,
                (id >> 3) * 64, (id & 7) * 64, nullptr);
  } else if (id < 144) {                // pv: M=512, N=1024 -> 8x16 tiles
    int t = id - 16;
    mfma_gemm64(xv, 512, Wkv, 1024, ws + WS_PV, 1024,
                (t >> 4) * 64, (t & 15) * 64, nullptr);
  } else {                              // pa: uses Wkv[:, 512:]
    int t = id - 144;
    mfma_gemm64(xa, 512, Wkv + 512, 1024, ws + WS_PA, 1024,
                (t >> 4) * 64, (t & 15) * 64, nullptr);
  }
}

// K3: out = hout @ Wproj.T + bproj. M=128,N=512 -> 2x8 = 16 blocks x 256 thr.
__global__ __launch_bounds__(256) void proj_out_kernel(
    const float* __restrict__ ws, const float* __restrict__ Wproj,
    const float* __restrict__ bproj, float* __restrict__ out)
{
  mfma_gemm64(ws + WS_HOUT, 512, Wproj, 512, out, 512,
              (int)(blockIdx.x >> 3) * 64, (int)(blockIdx.x & 7) * 64, bproj);
}

// ---------------------------------------------------------------------------
// K2: factorized attention (fp32). Grid = 16 (b,h) x 4 q-row-tiles = 64
// blocks, 256 threads (4 waves). For each side s in {pv, pa}:
//   A[n,i] = (scale*q[n,:]) . kpart[i,:]   (kpart = side[:, h*64 : h*64+64])
//   P = softmax_i(A) (wave-parallel over 256 keys, rows held in registers)
//   oacc += P @ vpart                      (vpart = side[:, 512+h*64 : ...])
// K/V staged to LDS in 128-row halves.
// ---------------------------------------------------------------------------
__global__ __launch_bounds__(256) void attn_kernel(float* __restrict__ ws)
{
  const float* qlin = ws + WS_Q;
  float* hout = ws + WS_HOUT;

  const int blk = blockIdx.x;
  const int bh = blk >> 2;              // 0..15
  const int ntile = blk & 3;            // 0..3 (16 q-rows each)
  const int b = bh >> 3, h = bh & 7;
  const int n0 = ntile * 16;

  __shared__ float q_s[16][64];         // 4 KB  (scaled q tile)
  __shared__ float kv_s[128][68];       // 34 KB (K or V half, padded)
  __shared__ float P_s[16][260];        // 16.25 KB (normalized probs)

  const int tid = threadIdx.x;
  const int w = tid >> 6;               // wave 0..3
  const int lane = tid & 63;

  { // stage q, folding in scale = 1/8
    int r = tid >> 4, c = tid & 15;
    float4 v = *reinterpret_cast<const float4*>(
        &qlin[(size_t)(b * 64 + n0 + r) * 512 + h * 64 + c * 4]);
    v.x *= 0.125f; v.y *= 0.125f; v.z *= 0.125f; v.w *= 0.125f;
    *reinterpret_cast<float4*>(&q_s[r][c * 4]) = v;
  }

  float4 oacc[2][2];
  #pragma unroll
  for (int r = 0; r < 2; ++r)
    #pragma unroll
    for (int c = 0; c < 2; ++c) oacc[r][c] = make_float4(0.f, 0.f, 0.f, 0.f);

  const int gn2 = lane >> 3;            // PV: rows 2*gn2 + {0,1}
  const int gd2 = lane & 7;             // PV: d-chunks 2*gd2 + {0,1}

  for (int side = 0; side < 2; ++side) {
    const float* src = (side == 0) ? (ws + WS_PV) : (ws + WS_PA);

    float sc[4][4];
    #pragma unroll
    for (int i = 0; i < 4; ++i)
      #pragma unroll
      for (int j = 0; j < 4; ++j) sc[i][j] = 0.f;

    for (int half = 0; half < 2; ++half) {
      __syncthreads();                  // prev phase done reading kv_s
      #pragma unroll
      for (int s = 0; s < 8; ++s) {     // stage K half: 128 rows x 16 chunks
        int idx = tid + s * 256;
        int r = idx >> 4, c = idx & 15;
        *reinterpret_cast<float4*>(&kv_s[r][c * 4]) =
          *reinterpret_cast<const float4*>(
            &src[(size_t)(b * 256 + half * 128 + r) * 1024 + h * 64 + c * 4]);
      }
      __syncthreads();
      #pragma unroll
      for (int dc = 0; dc < 16; ++dc) {
        float4 q4[4], k4[2];
        #pragma unroll
        for (int ni = 0; ni < 4; ++ni)
          q4[ni] = *reinterpret_cast<const float4*>(&q_s[w * 4 + ni][dc * 4]);
        #pragma unroll
        for (int i2 = 0; i2 < 2; ++i2)
          k4[i2] = *reinterpret_cast<const float4*>(&kv_s[lane + 64 * i2][dc * 4]);
        #pragma unroll
        for (int ni = 0; ni < 4; ++ni)
          #pragma unroll
          for (int i2 = 0; i2 < 2; ++i2)
            sc[ni][half * 2 + i2] += q4[ni].x * k4[i2].x + q4[ni].y * k4[i2].y
                                   + q4[ni].z * k4[i2].z + q4[ni].w * k4[i2].w;
      }
    }

    #pragma unroll
    for (int ni = 0; ni < 4; ++ni) {
      float m = fmaxf(fmaxf(sc[ni][0], sc[ni][1]), fmaxf(sc[ni][2], sc[ni][3]));
      #pragma unroll
      for (int off = 32; off >= 1; off >>= 1)
        m = fmaxf(m, __shfl_xor(m, off));
      float e[4], ls = 0.f;
      #pragma unroll
      for (int ii = 0; ii < 4; ++ii) { e[ii] = __expf(sc[ni][ii] - m); ls += e[ii]; }
      #pragma unroll
      for (int off = 32; off >= 1; off >>= 1)
        ls += __shfl_xor(ls, off);
      float inv = 1.0f / ls;
      #pragma unroll
      for (int ii = 0; ii < 4; ++ii)
        P_s[w * 4 + ni][lane + 64 * ii] = e[ii] * inv;
    }

    for (int half = 0; half < 2; ++half) {
      __syncthreads();                  // scores/PV done reading kv_s
      #pragma unroll
      for (int s = 0; s < 8; ++s) {     // stage V half (cols 512 + h*64 ..)
        int idx = tid + s * 256;
        int r = idx >> 4, c = idx & 15;
        *reinterpret_cast<float4*>(&kv_s[r][c * 4]) =
          *reinterpret_cast<const float4*>(
            &src[(size_t)(b * 256 + half * 128 + r) * 1024 + 512 + h * 64 + c * 4]);
      }
      __syncthreads();
      #pragma unroll
      for (int ic = 0; ic < 8; ++ic) {
        int i0l = w * 32 + ic * 4;          // local row in kv_s
        int i0g = half * 128 + i0l;         // column in P_s
        float4 p4[2];
        #pragma unroll
        for (int r = 0; r < 2; ++r)
          p4[r] = *reinterpret_cast<const float4*>(&P_s[gn2 * 2 + r][i0g]);
        float4 v4[4][2];
        #pragma unroll
        for (int m = 0; m < 4; ++m)
          #pragma unroll
          for (int c = 0; c < 2; ++c)
            v4[m][c] = *reinterpret_cast<const float4*>(&kv_s[i0l + m][(gd2 * 2 + c) * 4]);
        #pragma unroll
        for (int r = 0; r < 2; ++r)
          #pragma unroll
          for (int c = 0; c < 2; ++c) {
            oacc[r][c].x += p4[r].x * v4[0][c].x + p4[r].y * v4[1][c].x
                          + p4[r].z * v4[2][c].x + p4[r].w * v4[3][c].x;
            oacc[r][c].y += p4[r].x * v4[0][c].y + p4[r].y * v4[1][c].y
                          + p4[r].z * v4[2][c].y + p4[r].w * v4[3][c].y;
            oacc[r][c].z += p4[r].x * v4[0][c].z + p4[r].y * v4[1][c].z
                          + p4[r].z * v4[2][c].z + p4[r].w * v4[3][c].z;
            oacc[r][c].w += p4[r].x * v4[0][c].w + p4[r].y * v4[1][c].w
                          + p4[r].z * v4[2][c].w + p4[r].w * v4[3][c].w;
          }
      }
    }
  } // side

  // ---- cross-wave reduction of PV partials (reuse kv_s as [4][16][64])
  __syncthreads();
  float* red = &kv_s[0][0];
  #pragma unroll
  for (int r = 0; r < 2; ++r)
    #pragma unroll
    for (int c = 0; c < 2; ++c)
      *reinterpret_cast<float4*>(
        &red[(size_t)w * 1024 + (gn2 * 2 + r) * 64 + (gd2 * 2 + c) * 4]) = oacc[r][c];
  __syncthreads();
  {
    int n = tid >> 4, dc = tid & 15;
    float4 sum = *reinterpret_cast<const float4*>(&red[(size_t)n * 64 + dc * 4]);
    #pragma unroll
    for (int ww = 1; ww < 4; ++ww) {
      float4 t = *reinterpret_cast<const float4*>(
          &red[(size_t)ww * 1024 + n * 64 + dc * 4]);
      sum.x += t.x; sum.y += t.y; sum.z += t.z; sum.w += t.w;
    }
    *reinterpret_cast<float4*>(
        &hout[(size_t)(b * 64 + n0 + n) * 512 + h * 64 + dc * 4]) = sum;
  }
}

extern "C" void kernel_launch(void* const* d_in, const int* in_sizes, int n_in,
                              void* d_out, int out_size, void* d_ws, size_t ws_size,
                              hipStream_t stream) {
  const float* xmm   = (const float*)d_in[0];  // [2,64,512]
  const float* xa    = (const float*)d_in[1];  // [2,256,512]
  const float* xv    = (const float*)d_in[2];  // [2,256,512]
  const float* Wq    = (const float*)d_in[3];  // [512,512]
  const float* Wkv   = (const float*)d_in[4];  // [1024,1024]
  const float* Wproj = (const float*)d_in[5];  // [512,512]
  const float* bproj = (const float*)d_in[6];  // [512]
  float* out = (float*)d_out;                  // [2,64,512]
  float* ws  = (float*)d_ws;                   // needs 4.5 MB

  fused_proj_kernel<<<272, 256, 0, stream>>>(xmm, xa, xv, Wq, Wkv, ws);
  attn_kernel<<<64, 256, 0, stream>>>(ws);
  proj_out_kernel<<<16, 256, 0, stream>>>(ws, Wproj, bproj, out);
}

// Round 4
// 40.441 us; speedup vs baseline: 3.2265x; 1.2509x over previous
//
#include <hip/hip_runtime.h>

// B=2, N_mm=64, N_a=N_v=256, DIM=512, H=8, hd=64, scale=1/8.
// Factorized: softmax over (i,j) grid with logits Av_i+Aa_j, values vv_i+va_j
// separates EXACTLY into the SUM of two independently-normalized 256-key
// attentions:  out = (Σ_i softmax_i(Av) vv_i) + (Σ_j softmax_j(Aa) va_j).
// (NOT a flash-style union merge — each side normalizes by its own sum.)
//
// Workspace layout:
//   f16 region (units = _Float16):
//     OQ   = 0       : q*scale        [128 rows][512]        (row = b*64+n)
//     OK(s)= 65536+s*262144 : K-part  [512 rows][512 cols]   (row = b*256+key)
//     OVT(s)=589824+s*262144: V-part^T[512 d'][512 rows]     (d' = col-512)
//   f32 region:
//     hout at f16-offset 1114112: [128][512] f32
// total 2490368 bytes.

#define OQ   0
#define OKP  65536
#define OVT  589824
#define SIDESZ 262144
#define OHOUT16 1114112   // f16 units; cast to float* at this element offset

typedef _Float16 f16x8 __attribute__((ext_vector_type(8)));
typedef _Float16 f16x4 __attribute__((ext_vector_type(4)));
typedef float f32x4 __attribute__((ext_vector_type(4)));

// ---------------------------------------------------------------------------
// MFMA f16 GEMM core: C[M,N] = A[M,K=512] @ W[N,K=512]^T.
// 64x64 tile, 256 threads (2x2 waves of 32x32). fp32 inputs staged to
// swizzled f16 LDS. MODE epilogues:
//   0: q     -> f16, scale 1/8, row-major scatter
//   1: kv    -> f16; cols<512 row-major K-part; cols>=512 transposed V-part
//   2: final -> f32 + bias
// ---------------------------------------------------------------------------
__device__ __forceinline__ void stage_tile_f16(
    const float* __restrict__ g, int ld, int base, int k0,
    _Float16* __restrict__ lds, int sr, int sq)
{
  const float* p = &g[(size_t)(base + sr) * ld + k0 + sq * 16];
  float4 v0 = *reinterpret_cast<const float4*>(p);
  float4 v1 = *reinterpret_cast<const float4*>(p + 4);
  float4 v2 = *reinterpret_cast<const float4*>(p + 8);
  float4 v3 = *reinterpret_cast<const float4*>(p + 12);
  f16x8 h0 = {(_Float16)v0.x, (_Float16)v0.y, (_Float16)v0.z, (_Float16)v0.w,
              (_Float16)v1.x, (_Float16)v1.y, (_Float16)v1.z, (_Float16)v1.w};
  f16x8 h1 = {(_Float16)v2.x, (_Float16)v2.y, (_Float16)v2.z, (_Float16)v2.w,
              (_Float16)v3.x, (_Float16)v3.y, (_Float16)v3.z, (_Float16)v3.w};
  int c0 = (sq * 2) ^ (sr & 7);
  int c1 = (sq * 2 + 1) ^ (sr & 7);
  *reinterpret_cast<f16x8*>(&lds[sr * 64 + c0 * 8]) = h0;
  *reinterpret_cast<f16x8*>(&lds[sr * 64 + c1 * 8]) = h1;
}

template <int MODE>
__device__ __forceinline__ void mfma_gemm64(
    const float* __restrict__ A, int lda,
    const float* __restrict__ W, int ldw,
    int bm, int bn, int side,
    _Float16* __restrict__ ws16,
    float* __restrict__ Cf, int ldc, const float* __restrict__ bias)
{
  __shared__ _Float16 As[64 * 64];   // 8 KB
  __shared__ _Float16 Ws[64 * 64];   // 8 KB
  const int tid = threadIdx.x;
  const int lane = tid & 63;
  const int w = tid >> 6;
  const int wm = w >> 1, wn = w & 1;
  const int sr = tid >> 2;
  const int sq = tid & 3;

  f32x4 acc[2][2] = {};
  const int cl = lane & 15;
  const int kg = lane >> 4;

  for (int k0 = 0; k0 < 512; k0 += 64) {
    __syncthreads();
    stage_tile_f16(A, lda, bm, k0, As, sr, sq);
    stage_tile_f16(W, ldw, bn, k0, Ws, sr, sq);
    __syncthreads();
    #pragma unroll
    for (int ks = 0; ks < 2; ++ks) {
      f16x8 af[2], bf[2];
      #pragma unroll
      for (int mi = 0; mi < 2; ++mi) {
        int row = wm * 32 + mi * 16 + cl;
        int ch = (ks * 4 + kg) ^ (row & 7);
        af[mi] = *reinterpret_cast<const f16x8*>(&As[row * 64 + ch * 8]);
      }
      #pragma unroll
      for (int ni = 0; ni < 2; ++ni) {
        int col = wn * 32 + ni * 16 + cl;
        int ch = (ks * 4 + kg) ^ (col & 7);
        bf[ni] = *reinterpret_cast<const f16x8*>(&Ws[col * 64 + ch * 8]);
      }
      #pragma unroll
      for (int mi = 0; mi < 2; ++mi)
        #pragma unroll
        for (int ni = 0; ni < 2; ++ni)
          acc[mi][ni] = __builtin_amdgcn_mfma_f32_16x16x32_f16(
              af[mi], bf[ni], acc[mi][ni], 0, 0, 0);
    }
  }

  #pragma unroll
  for (int mi = 0; mi < 2; ++mi) {
    #pragma unroll
    for (int ni = 0; ni < 2; ++ni) {
      int row0 = bm + wm * 32 + mi * 16 + kg * 4;
      int col = bn + wn * 32 + ni * 16 + cl;
      if (MODE == 0) {
        _Float16* dst = ws16 + OQ + (size_t)row0 * 512 + col;
        #pragma unroll
        for (int r = 0; r < 4; ++r)
          dst[(size_t)r * 512] = (_Float16)(acc[mi][ni][r] * 0.125f);
      } else if (MODE == 1) {
        if (col < 512) {
          _Float16* dst = ws16 + OKP + (size_t)side * SIDESZ + (size_t)row0 * 512 + col;
          #pragma unroll
          for (int r = 0; r < 4; ++r)
            dst[(size_t)r * 512] = (_Float16)acc[mi][ni][r];
        } else {
          _Float16* dst = ws16 + OVT + (size_t)side * SIDESZ +
                          (size_t)(col - 512) * 512 + row0;
          f16x4 v = {(_Float16)acc[mi][ni][0], (_Float16)acc[mi][ni][1],
                     (_Float16)acc[mi][ni][2], (_Float16)acc[mi][ni][3]};
          *reinterpret_cast<f16x4*>(dst) = v;
        }
      } else {
        float bv = bias ? bias[col] : 0.f;
        #pragma unroll
        for (int r = 0; r < 4; ++r)
          Cf[(size_t)(row0 + r) * ldc + col] = acc[mi][ni][r] + bv;
      }
    }
  }
}

// K1: fused q / pv / pa projections. 272 blocks x 256 threads.
__global__ __launch_bounds__(256) void fused_proj_kernel(
    const float* __restrict__ xmm, const float* __restrict__ xa,
    const float* __restrict__ xv, const float* __restrict__ Wq,
    const float* __restrict__ Wkv, _Float16* __restrict__ ws16)
{
  const int id = blockIdx.x;
  if (id < 16) {                        // q: M=128, N=512 -> 2x8 tiles
    mfma_gemm64<0>(xmm, 512, Wq, 512, (id >> 3) * 64, (id & 7) * 64, 0,
                   ws16, nullptr, 0, nullptr);
  } else if (id < 144) {                // pv: M=512, N=1024 -> 8x16 tiles
    int t = id - 16;
    mfma_gemm64<1>(xv, 512, Wkv, 1024, (t >> 4) * 64, (t & 15) * 64, 0,
                   ws16, nullptr, 0, nullptr);
  } else {                              // pa: uses Wkv rows, cols 512..1023
    int t = id - 144;
    mfma_gemm64<1>(xa, 512, Wkv + 512, 1024, (t >> 4) * 64, (t & 15) * 64, 1,
                   ws16, nullptr, 0, nullptr);
  }
}

// K3: out = hout @ Wproj.T + bproj. 16 blocks x 256 threads.
__global__ __launch_bounds__(256) void proj_out_kernel(
    const _Float16* __restrict__ ws16, const float* __restrict__ Wproj,
    const float* __restrict__ bproj, float* __restrict__ out)
{
  const float* hout = (const float*)(ws16 + OHOUT16);
  mfma_gemm64<2>(hout, 512, Wproj, 512,
                 (int)(blockIdx.x >> 3) * 64, (int)(blockIdx.x & 7) * 64, 0,
                 nullptr, out, 512, bproj);
}

// ---------------------------------------------------------------------------
// K2: MFMA attention. Grid = 16 (b,h) x 2 q-halves = 32 blocks, 256 threads
// (4 waves: side = w&1, qtile16 = w>>1). Swapped QK (mfma(K,Q) -> S^T): lane
// owns 64 keys of q-row (lane&15); softmax = in-reg + 2 shuffles. P goes
// through XOR-swizzled LDS to become the PV A-operand; K/Q/V fragments load
// straight from L2-resident f16 workspace (no staging). Sides SUMMED with
// per-side normalization (exact factorization).
// ---------------------------------------------------------------------------
__global__ __launch_bounds__(256) void attn_kernel(
    const _Float16* __restrict__ ws16, float* __restrict__ hout)
{
  __shared__ _Float16 P_lds[4][16][256];          // 32 KB; overlaid by mbuf
  float* mbuf = reinterpret_cast<float*>(&P_lds[0][0][0]);  // [2][32][68]

  const int bh = blockIdx.x >> 1;
  const int qh = blockIdx.x & 1;        // q-half (32 rows)
  const int b = bh >> 3, h = bh & 7;

  const int tid = threadIdx.x;
  const int w = tid >> 6;
  const int lane = tid & 63;
  const int side = w & 1;
  const int qtl = w >> 1;               // 16-row tile within the half
  const int q0 = qh * 32 + qtl * 16;    // q-row base within 64
  const int l15 = lane & 15;
  const int g = lane >> 4;

  const _Float16* Kg = ws16 + OKP + (size_t)side * SIDESZ;
  const _Float16* VTg = ws16 + OVT + (size_t)side * SIDESZ;

  // Q B-fragments (scale already folded in K1)
  f16x8 qb[2];
  #pragma unroll
  for (int ks = 0; ks < 2; ++ks)
    qb[ks] = *reinterpret_cast<const f16x8*>(
        &ws16[OQ + (size_t)(b * 64 + q0 + l15) * 512 + h * 64 + ks * 32 + g * 8]);

  // ---- S^T = K @ Q^T : 16 key-fragments x 2 k-steps
  f32x4 st[16] = {};
  #pragma unroll
  for (int f = 0; f < 16; ++f) {
    #pragma unroll
    for (int ks = 0; ks < 2; ++ks) {
      f16x8 af = *reinterpret_cast<const f16x8*>(
          &Kg[(size_t)(b * 256 + f * 16 + l15) * 512 + h * 64 + ks * 32 + g * 8]);
      st[f] = __builtin_amdgcn_mfma_f32_16x16x32_f16(af, qb[ks], st[f], 0, 0, 0);
    }
  }

  // ---- softmax over this lane's 64 keys + butterfly across the 4 groups
  float m = st[0][0];
  #pragma unroll
  for (int f = 0; f < 16; ++f)
    #pragma unroll
    for (int r = 0; r < 4; ++r) m = fmaxf(m, st[f][r]);
  m = fmaxf(m, __shfl_xor(m, 16));
  m = fmaxf(m, __shfl_xor(m, 32));
  float lsum = 0.f;
  #pragma unroll
  for (int f = 0; f < 16; ++f)
    #pragma unroll
    for (int r = 0; r < 4; ++r) {
      float e = __expf(st[f][r] - m);
      st[f][r] = e;
      lsum += e;
    }
  lsum += __shfl_xor(lsum, 16);
  lsum += __shfl_xor(lsum, 32);
  // m cancels within each side's Ov/lv ratio; only lsum is needed downstream.

  // ---- write P (unnormalized e^{s-m}) to swizzled LDS: key 16f+4g+r, q=l15
  #pragma unroll
  for (int f = 0; f < 16; ++f) {
    f16x4 pk = {(_Float16)st[f][0], (_Float16)st[f][1],
                (_Float16)st[f][2], (_Float16)st[f][3]};
    int chunk = 2 * f + (g >> 1);
    int swz = chunk ^ (l15 & 7);
    *reinterpret_cast<f16x4*>(&P_lds[w][l15][swz * 8 + (g & 1) * 4]) = pk;
  }
  __syncthreads();

  // ---- O = P @ V : A-frags from P_lds, B-frags straight from VT (global)
  f32x4 oc[4] = {};
  #pragma unroll
  for (int ks = 0; ks < 8; ++ks) {
    f16x8 pa = *reinterpret_cast<const f16x8*>(
        &P_lds[w][l15][((4 * ks + g) ^ (l15 & 7)) * 8]);
    #pragma unroll
    for (int nf = 0; nf < 4; ++nf) {
      f16x8 vb = *reinterpret_cast<const f16x8*>(
          &VTg[(size_t)(h * 64 + nf * 16 + l15) * 512 + b * 256 + ks * 32 + g * 8]);
      oc[nf] = __builtin_amdgcn_mfma_f32_16x16x32_f16(pa, vb, oc[nf], 0, 0, 0);
    }
  }
  __syncthreads();                      // all waves done reading P_lds

  // ---- write O (rows q=4g+r) and per-q lsum into merge buffer [2][32][68]
  #pragma unroll
  for (int nf = 0; nf < 4; ++nf)
    #pragma unroll
    for (int r = 0; r < 4; ++r)
      mbuf[((size_t)side * 32 + qtl * 16 + 4 * g + r) * 68 + nf * 16 + l15] =
          oc[nf][r];
  if (g == 0)
    mbuf[((size_t)side * 32 + qtl * 16 + l15) * 68 + 64] = lsum;
  __syncthreads();

  // ---- combine sides (SUM of per-side-normalized attentions):
  //      out = Ov/lv + Oa/la.  32 q x 64 d; thread -> (q, 8 d)
  {
    int q = tid >> 3, d0 = (tid & 7) * 8;
    const float* rv = &mbuf[(size_t)q * 68];
    const float* ra = &mbuf[(size_t)(32 + q) * 68];
    float invv = 1.0f / rv[64];
    float inva = 1.0f / ra[64];
    float4 o0, o1;
    const float4 v0 = *reinterpret_cast<const float4*>(rv + d0);
    const float4 v1 = *reinterpret_cast<const float4*>(rv + d0 + 4);
    const float4 a0 = *reinterpret_cast<const float4*>(ra + d0);
    const float4 a1 = *reinterpret_cast<const float4*>(ra + d0 + 4);
    o0.x = v0.x * invv + a0.x * inva; o0.y = v0.y * invv + a0.y * inva;
    o0.z = v0.z * invv + a0.z * inva; o0.w = v0.w * invv + a0.w * inva;
    o1.x = v1.x * invv + a1.x * inva; o1.y = v1.y * invv + a1.y * inva;
    o1.z = v1.z * invv + a1.z * inva; o1.w = v1.w * invv + a1.w * inva;
    float* dst = &hout[(size_t)(b * 64 + qh * 32 + q) * 512 + h * 64 + d0];
    *reinterpret_cast<float4*>(dst) = o0;
    *reinterpret_cast<float4*>(dst + 4) = o1;
  }
}

extern "C" void kernel_launch(void* const* d_in, const int* in_sizes, int n_in,
                              void* d_out, int out_size, void* d_ws, size_t ws_size,
                              hipStream_t stream) {
  const float* xmm   = (const float*)d_in[0];  // [2,64,512]
  const float* xa    = (const float*)d_in[1];  // [2,256,512]
  const float* xv    = (const float*)d_in[2];  // [2,256,512]
  const float* Wq    = (const float*)d_in[3];  // [512,512]
  const float* Wkv   = (const float*)d_in[4];  // [1024,1024]
  const float* Wproj = (const float*)d_in[5];  // [512,512]
  const float* bproj = (const float*)d_in[6];  // [512]
  float* out = (float*)d_out;                  // [2,64,512]
  _Float16* ws16 = (_Float16*)d_ws;            // needs ~2.4 MB
  float* hout = (float*)(ws16 + OHOUT16);

  fused_proj_kernel<<<272, 256, 0, stream>>>(xmm, xa, xv, Wq, Wkv, ws16);
  attn_kernel<<<32, 256, 0, stream>>>(ws16, hout);
  proj_out_kernel<<<16, 256, 0, stream>>>(ws16, Wproj, bproj, out);
}

// Round 5
// 37.036 us; speedup vs baseline: 3.5232x; 1.0920x over previous
//
#include <hip/hip_runtime.h>

// B=2, N_mm=64, N_a=N_v=256, DIM=512, H=8, hd=64, scale=1/8.
// Factorized: softmax over (i,j) grid with logits Av_i+Aa_j, values vv_i+va_j
// = SUM of two independently-normalized 256-key attentions:
//   out = (Σ_i softmax_i(Av) vv_i) + (Σ_j softmax_j(Aa) va_j).
//
// Workspace (f16 units unless noted), per-(b,h) slab layouts for attn:
//   Q16 : [b][h][n(64)][d(64)]          q*scale, slab 8 KB
//   K16 : [side][b][h][key(256)][d(64)] slab 32 KB
//   VT16: [side][b][h][d(64)][key(256)] slab 32 KB
//   hv/ha: two f32 [128][512] per-side normalized attention outputs.

#define OQ16   0
#define OK16   65536
#define OVT16  589824
#define SIDESZ 262144
#define OHOUT16 1114112   // f16 units; f32 hv here, ha at +65536 floats

typedef _Float16 f16x8 __attribute__((ext_vector_type(8)));
typedef _Float16 f16x4 __attribute__((ext_vector_type(4)));
typedef float f32x4 __attribute__((ext_vector_type(4)));

// ---------------------------------------------------------------------------
// MFMA f16 GEMM core: C[M,N] = A[M,K=512] @ W[N,K=512]^T.
// 64x64 tile, 256 threads (2x2 waves of 32x32). fp32 inputs staged to
// swizzled f16 LDS (16B-chunk XOR swizzle). MODE epilogues:
//   0: q     -> f16 * 1/8 into Q16 slabs
//   1: kv    -> f16; cols<512 K16 slabs; cols>=512 transposed VT16 slabs
//   2: final -> f32 + bias (A-operand = A + A2 summed during staging)
// ---------------------------------------------------------------------------
__device__ __forceinline__ void stage_tile_f16(
    const float* __restrict__ g, const float* __restrict__ g2, int ld,
    int base, int k0, _Float16* __restrict__ lds, int sr, int sq)
{
  const float* p = &g[(size_t)(base + sr) * ld + k0 + sq * 16];
  float4 v0 = *reinterpret_cast<const float4*>(p);
  float4 v1 = *reinterpret_cast<const float4*>(p + 4);
  float4 v2 = *reinterpret_cast<const float4*>(p + 8);
  float4 v3 = *reinterpret_cast<const float4*>(p + 12);
  if (g2) {
    const float* p2 = &g2[(size_t)(base + sr) * ld + k0 + sq * 16];
    float4 u0 = *reinterpret_cast<const float4*>(p2);
    float4 u1 = *reinterpret_cast<const float4*>(p2 + 4);
    float4 u2 = *reinterpret_cast<const float4*>(p2 + 8);
    float4 u3 = *reinterpret_cast<const float4*>(p2 + 12);
    v0.x += u0.x; v0.y += u0.y; v0.z += u0.z; v0.w += u0.w;
    v1.x += u1.x; v1.y += u1.y; v1.z += u1.z; v1.w += u1.w;
    v2.x += u2.x; v2.y += u2.y; v2.z += u2.z; v2.w += u2.w;
    v3.x += u3.x; v3.y += u3.y; v3.z += u3.z; v3.w += u3.w;
  }
  f16x8 h0 = {(_Float16)v0.x, (_Float16)v0.y, (_Float16)v0.z, (_Float16)v0.w,
              (_Float16)v1.x, (_Float16)v1.y, (_Float16)v1.z, (_Float16)v1.w};
  f16x8 h1 = {(_Float16)v2.x, (_Float16)v2.y, (_Float16)v2.z, (_Float16)v2.w,
              (_Float16)v3.x, (_Float16)v3.y, (_Float16)v3.z, (_Float16)v3.w};
  int c0 = (sq * 2) ^ (sr & 7);
  int c1 = (sq * 2 + 1) ^ (sr & 7);
  *reinterpret_cast<f16x8*>(&lds[sr * 64 + c0 * 8]) = h0;
  *reinterpret_cast<f16x8*>(&lds[sr * 64 + c1 * 8]) = h1;
}

template <int MODE>
__device__ __forceinline__ void mfma_gemm64(
    const float* __restrict__ A, const float* __restrict__ A2, int lda,
    const float* __restrict__ W, int ldw,
    int bm, int bn, int side,
    _Float16* __restrict__ ws16,
    float* __restrict__ Cf, int ldc, const float* __restrict__ bias)
{
  __shared__ _Float16 As[64 * 64];   // 8 KB
  __shared__ _Float16 Ws[64 * 64];   // 8 KB
  const int tid = threadIdx.x;
  const int lane = tid & 63;
  const int w = tid >> 6;
  const int wm = w >> 1, wn = w & 1;
  const int sr = tid >> 2;
  const int sq = tid & 3;

  f32x4 acc[2][2] = {};
  const int cl = lane & 15;
  const int kg = lane >> 4;

  for (int k0 = 0; k0 < 512; k0 += 64) {
    __syncthreads();
    stage_tile_f16(A, A2, lda, bm, k0, As, sr, sq);
    stage_tile_f16(W, nullptr, ldw, bn, k0, Ws, sr, sq);
    __syncthreads();
    #pragma unroll
    for (int ks = 0; ks < 2; ++ks) {
      f16x8 af[2], bf[2];
      #pragma unroll
      for (int mi = 0; mi < 2; ++mi) {
        int row = wm * 32 + mi * 16 + cl;
        int ch = (ks * 4 + kg) ^ (row & 7);
        af[mi] = *reinterpret_cast<const f16x8*>(&As[row * 64 + ch * 8]);
      }
      #pragma unroll
      for (int ni = 0; ni < 2; ++ni) {
        int col = wn * 32 + ni * 16 + cl;
        int ch = (ks * 4 + kg) ^ (col & 7);
        bf[ni] = *reinterpret_cast<const f16x8*>(&Ws[col * 64 + ch * 8]);
      }
      #pragma unroll
      for (int mi = 0; mi < 2; ++mi)
        #pragma unroll
        for (int ni = 0; ni < 2; ++ni)
          acc[mi][ni] = __builtin_amdgcn_mfma_f32_16x16x32_f16(
              af[mi], bf[ni], acc[mi][ni], 0, 0, 0);
    }
  }

  #pragma unroll
  for (int mi = 0; mi < 2; ++mi) {
    #pragma unroll
    for (int ni = 0; ni < 2; ++ni) {
      int row0 = bm + wm * 32 + mi * 16 + kg * 4;
      int col = bn + wn * 32 + ni * 16 + cl;
      if (MODE == 0) {
        // Q16[b][h][n][d], row0 = b*64+n, col = h*64+d
        int b = row0 >> 6, n = row0 & 63, h = col >> 6, d = col & 63;
        _Float16* dst = ws16 + OQ16 + (((size_t)b * 8 + h) * 64 + n) * 64 + d;
        #pragma unroll
        for (int r = 0; r < 4; ++r)
          dst[(size_t)r * 64] = (_Float16)(acc[mi][ni][r] * 0.125f);
      } else if (MODE == 1) {
        int b = row0 >> 8, key = row0 & 255;
        if (col < 512) {
          // K16[side][b][h][key][d]
          int h = col >> 6, d = col & 63;
          _Float16* dst = ws16 + OK16 + (size_t)side * SIDESZ +
                          (((size_t)b * 8 + h) * 256 + key) * 64 + d;
          #pragma unroll
          for (int r = 0; r < 4; ++r)
            dst[(size_t)r * 64] = (_Float16)acc[mi][ni][r];
        } else {
          // VT16[side][b][h][d][key], 4 consecutive keys -> contiguous
          int dp = col - 512;
          int h = dp >> 6, d = dp & 63;
          _Float16* dst = ws16 + OVT16 + (size_t)side * SIDESZ +
                          (((size_t)b * 8 + h) * 64 + d) * 256 + key;
          f16x4 v = {(_Float16)acc[mi][ni][0], (_Float16)acc[mi][ni][1],
                     (_Float16)acc[mi][ni][2], (_Float16)acc[mi][ni][3]};
          *reinterpret_cast<f16x4*>(dst) = v;
        }
      } else {
        float bv = bias ? bias[col] : 0.f;
        #pragma unroll
        for (int r = 0; r < 4; ++r)
          Cf[(size_t)(row0 + r) * ldc + col] = acc[mi][ni][r] + bv;
      }
    }
  }
}

// K1: fused q / pv / pa projections. 272 blocks x 256 threads.
__global__ __launch_bounds__(256) void fused_proj_kernel(
    const float* __restrict__ xmm, const float* __restrict__ xa,
    const float* __restrict__ xv, const float* __restrict__ Wq,
    const float* __restrict__ Wkv, _Float16* __restrict__ ws16)
{
  const int id = blockIdx.x;
  if (id < 16) {                        // q: M=128, N=512 -> 2x8 tiles
    mfma_gemm64<0>(xmm, nullptr, 512, Wq, 512, (id >> 3) * 64, (id & 7) * 64,
                   0, ws16, nullptr, 0, nullptr);
  } else if (id < 144) {                // pv: M=512, N=1024 -> 8x16 tiles
    int t = id - 16;
    mfma_gemm64<1>(xv, nullptr, 512, Wkv, 1024, (t >> 4) * 64, (t & 15) * 64,
                   0, ws16, nullptr, 0, nullptr);
  } else {                              // pa: Wkv rows, cols 512..1023
    int t = id - 144;
    mfma_gemm64<1>(xa, nullptr, 512, Wkv + 512, 1024, (t >> 4) * 64,
                   (t & 15) * 64, 1, ws16, nullptr, 0, nullptr);
  }
}

// K3: out = (hv + ha) @ Wproj.T + bproj. 16 blocks x 256 threads.
__global__ __launch_bounds__(256) void proj_out_kernel(
    const _Float16* __restrict__ ws16, const float* __restrict__ Wproj,
    const float* __restrict__ bproj, float* __restrict__ out)
{
  const float* hv = (const float*)(ws16 + OHOUT16);
  const float* ha = hv + 65536;
  mfma_gemm64<2>(hv, ha, 512, Wproj, 512,
                 (int)(blockIdx.x >> 3) * 64, (int)(blockIdx.x & 7) * 64, 0,
                 nullptr, out, 512, bproj);
}

// ---------------------------------------------------------------------------
// K2: MFMA attention. Grid = 128 blocks: x = (bh<<3) | (qtl<<1) | side.
// 4 waves per block over ONE (side, 16-q-row tile):
//   QK^T: waves split 256 keys (64 each), swapped mfma(K,Q) -> S^T, so each
//         lane owns 16 scores for q-row (lane&15).
//   softmax: per-wave (m) -> LDS merge -> exact e^{s-M}; l merged via LDS.
//   PV:   waves split d (16 cols each) over ALL 256 keys from P_lds.
// Writes per-side normalized O to hv/ha; K3 sums the sides (linear => exact).
// ---------------------------------------------------------------------------
__global__ __launch_bounds__(256) void attn_kernel(
    const _Float16* __restrict__ ws16, float* __restrict__ hv,
    float* __restrict__ ha)
{
  __shared__ _Float16 P_lds[16][256];   // 8 KB, XOR-swizzled 16B chunks
  __shared__ float m_s[4][16];
  __shared__ float l_s[4][16];

  const int x = blockIdx.x;
  const int side = x & 1;
  const int qtl = (x >> 1) & 3;
  const int bh = x >> 3;                // b*8+h
  const int b = bh >> 3;

  const int tid = threadIdx.x;
  const int w = tid >> 6;
  const int lane = tid & 63;
  const int l15 = lane & 15;
  const int g = lane >> 4;

  const _Float16* slabQ = ws16 + OQ16 + (size_t)bh * 4096;
  const _Float16* slabK = ws16 + OK16 + (size_t)side * SIDESZ + (size_t)bh * 16384;
  const _Float16* slabV = ws16 + OVT16 + (size_t)side * SIDESZ + (size_t)bh * 16384;

  // Q B-fragments for q-rows qtl*16 + (0..15); scale folded in K1.
  f16x8 qb[2];
  #pragma unroll
  for (int ks = 0; ks < 2; ++ks)
    qb[ks] = *reinterpret_cast<const f16x8*>(
        &slabQ[(size_t)(qtl * 16 + l15) * 64 + ks * 32 + g * 8]);

  // ---- S^T for this wave's 64 keys: frag f covers keys w*64+f*16+(0..15)
  f32x4 st[4] = {};
  #pragma unroll
  for (int f = 0; f < 4; ++f) {
    #pragma unroll
    for (int ks = 0; ks < 2; ++ks) {
      f16x8 af = *reinterpret_cast<const f16x8*>(
          &slabK[(size_t)(w * 64 + f * 16 + l15) * 64 + ks * 32 + g * 8]);
      st[f] = __builtin_amdgcn_mfma_f32_16x16x32_f16(af, qb[ks], st[f], 0, 0, 0);
    }
  }
  // st[f][r] = S[key = w*64+f*16+4g+r][q = l15]

  // ---- per-wave max over this lane's keys, then cross-g, publish to LDS
  float m = st[0][0];
  #pragma unroll
  for (int f = 0; f < 4; ++f)
    #pragma unroll
    for (int r = 0; r < 4; ++r) m = fmaxf(m, st[f][r]);
  m = fmaxf(m, __shfl_xor(m, 16));
  m = fmaxf(m, __shfl_xor(m, 32));
  if (g == 0) m_s[w][l15] = m;
  __syncthreads();

  // ---- global max over 4 waves; exp; partial sum; P -> swizzled LDS
  float M = fmaxf(fmaxf(m_s[0][l15], m_s[1][l15]),
                  fmaxf(m_s[2][l15], m_s[3][l15]));
  float lsum = 0.f;
  #pragma unroll
  for (int f = 0; f < 4; ++f)
    #pragma unroll
    for (int r = 0; r < 4; ++r) {
      float e = __expf(st[f][r] - M);
      st[f][r] = e;
      lsum += e;
    }
  lsum += __shfl_xor(lsum, 16);
  lsum += __shfl_xor(lsum, 32);
  if (g == 0) l_s[w][l15] = lsum;

  #pragma unroll
  for (int f = 0; f < 4; ++f) {
    f16x4 pk = {(_Float16)st[f][0], (_Float16)st[f][1],
                (_Float16)st[f][2], (_Float16)st[f][3]};
    int chunk = w * 8 + 2 * f + (g >> 1);
    int swz = chunk ^ (l15 & 7);
    *reinterpret_cast<f16x4*>(&P_lds[l15][swz * 8 + (g & 1) * 4]) = pk;
  }
  __syncthreads();

  // ---- L per output row q' = 4g+r (sum of wave partials)
  f32x4 L4 = {};
  #pragma unroll
  for (int w2 = 0; w2 < 4; ++w2) {
    f32x4 lw = *reinterpret_cast<const f32x4*>(&l_s[w2][g * 4]);
    L4 += lw;
  }

  // ---- PV: this wave owns d-frag w (cols w*16..w*16+15), all 256 keys
  f32x4 oc = {};
  #pragma unroll
  for (int ks = 0; ks < 8; ++ks) {
    f16x8 pa = *reinterpret_cast<const f16x8*>(
        &P_lds[l15][((4 * ks + g) ^ (l15 & 7)) * 8]);
    f16x8 vb = *reinterpret_cast<const f16x8*>(
        &slabV[(size_t)(w * 16 + l15) * 256 + ks * 32 + g * 8]);
    oc = __builtin_amdgcn_mfma_f32_16x16x32_f16(pa, vb, oc, 0, 0, 0);
  }
  // oc[r]: row q' = 4g+r, col d = w*16+l15

  float* houtS = side ? ha : hv;
  const int h = bh & 7;
  #pragma unroll
  for (int r = 0; r < 4; ++r) {
    houtS[(size_t)(b * 64 + qtl * 16 + 4 * g + r) * 512 +
          h * 64 + w * 16 + l15] = oc[r] * (1.0f / L4[r]);
  }
}

extern "C" void kernel_launch(void* const* d_in, const int* in_sizes, int n_in,
                              void* d_out, int out_size, void* d_ws, size_t ws_size,
                              hipStream_t stream) {
  const float* xmm   = (const float*)d_in[0];  // [2,64,512]
  const float* xa    = (const float*)d_in[1];  // [2,256,512]
  const float* xv    = (const float*)d_in[2];  // [2,256,512]
  const float* Wq    = (const float*)d_in[3];  // [512,512]
  const float* Wkv   = (const float*)d_in[4];  // [1024,1024]
  const float* Wproj = (const float*)d_in[5];  // [512,512]
  const float* bproj = (const float*)d_in[6];  // [512]
  float* out = (float*)d_out;                  // [2,64,512]
  _Float16* ws16 = (_Float16*)d_ws;            // ~2.8 MB used
  float* hv = (float*)(ws16 + OHOUT16);
  float* ha = hv + 65536;

  fused_proj_kernel<<<272, 256, 0, stream>>>(xmm, xa, xv, Wq, Wkv, ws16);
  attn_kernel<<<128, 256, 0, stream>>>(ws16, hv, ha);
  proj_out_kernel<<<16, 256, 0, stream>>>(ws16, Wproj, bproj, out);
}